// Round 1
// baseline (462.289 us; speedup 1.0000x reference)
//
#include <hip/hip_runtime.h>
#include <cstdint>
#include <cstddef>
#include <cmath>

#pragma clang fp contract(off)

namespace {

constexpr int kCandMax = 4096;

__device__ __constant__ int c_N[5] = {196608, 49152, 12288, 3072, 768};
__device__ __constant__ int c_K[5] = {1000, 1000, 1000, 1000, 768};

struct RPNParams {
  const float* deltas[5];
  const float* ctr[5];
  const float* anchors[5];
  float* scores;         // [8][5][1024] masked scores, per-level sorted desc
  float* boxes;          // [8][5][1024][4] clipped boxes, per-level sorted
  unsigned char* keep;   // [8][5][1024]
  unsigned int* mask;    // [8][5][1024][32] suppression bits (j in bits, row i)
  unsigned int* ghist0;  // [40][256]
  unsigned int* ghist1;  // [40][256]
  float* out;            // [8][1000][5]
};

// monotonic float->uint map (larger float => larger uint)
__device__ __forceinline__ unsigned int fkey(float f) {
  unsigned int u = __float_as_uint(f);
  return (u & 0x80000000u) ? ~u : (u | 0x80000000u);
}

__device__ __forceinline__ unsigned long long shfl64(unsigned long long v, int src) {
  unsigned int lo = __shfl((unsigned int)(v & 0xFFFFFFFFu), src, 64);
  unsigned int hi = __shfl((unsigned int)(v >> 32), src, 64);
  return ((unsigned long long)hi << 32) | (unsigned long long)lo;
}

// ---------------- Phase 1a: 8-bit histogram of score keys ----------------
__global__ __launch_bounds__(256) void k_hist0(RPNParams P) {
  int bl = blockIdx.x, b = bl / 5, l = bl % 5;
  int N = c_N[l];
  int chunk = (N + 31) / 32;
  int i0 = blockIdx.y * chunk;
  int i1 = i0 + chunk; if (i1 > N) i1 = N;
  const float* ctr = P.ctr[l] + (size_t)b * N;
  __shared__ unsigned int wh[4][256];
  int tid = threadIdx.x, wid = tid >> 6;
  for (int i = tid; i < 1024; i += 256) ((unsigned int*)wh)[i] = 0u;
  __syncthreads();
  for (int i = i0 + tid; i < i1; i += 256) {
    unsigned int u = fkey(ctr[i]);
    atomicAdd(&wh[wid][u >> 24], 1u);
  }
  __syncthreads();
  int bin = tid;
  unsigned int s = wh[0][bin] + wh[1][bin] + wh[2][bin] + wh[3][bin];
  if (s) atomicAdd(&P.ghist0[bl * 256 + bin], s);
}

// ---------------- Phase 1b: refine to 16-bit within chosen top byte ------
__global__ __launch_bounds__(256) void k_hist1(RPNParams P) {
  int bl = blockIdx.x, b = bl / 5, l = bl % 5;
  int N = c_N[l], K = c_K[l];
  int chunk = (N + 31) / 32;
  int i0 = blockIdx.y * chunk;
  int i1 = i0 + chunk; if (i1 > N) i1 = N;
  const float* ctr = P.ctr[l] + (size_t)b * N;
  __shared__ unsigned int wh[4][256];
  __shared__ unsigned int sV0;
  int tid = threadIdx.x, wid = tid >> 6;
  if (tid < 256) wh[0][tid] = P.ghist0[bl * 256 + tid];
  __syncthreads();
  if (tid == 0) {
    unsigned int kk = (unsigned int)K, cum = 0;
    int v = 255;
    for (; v > 0; --v) { unsigned int x = wh[0][v]; if (cum + x >= kk) break; cum += x; }
    sV0 = (unsigned int)v;
  }
  __syncthreads();
  unsigned int v0 = sV0;
  for (int i = tid; i < 1024; i += 256) ((unsigned int*)wh)[i] = 0u;
  __syncthreads();
  for (int i = i0 + tid; i < i1; i += 256) {
    unsigned int u = fkey(ctr[i]);
    if ((u >> 24) == v0) atomicAdd(&wh[wid][(u >> 16) & 255u], 1u);
  }
  __syncthreads();
  int bin = tid;
  unsigned int s = wh[0][bin] + wh[1][bin] + wh[2][bin] + wh[3][bin];
  if (s) atomicAdd(&P.ghist1[bl * 256 + bin], s);
}

// ---- Phase 1c: threshold, compact candidates, sort, decode+clip boxes ----
__global__ __launch_bounds__(1024) void k_select(RPNParams P) {
  int bl = blockIdx.x, b = bl / 5, l = bl % 5;
  int N = c_N[l], K = c_K[l];
  const float* ctr = P.ctr[l] + (size_t)b * N;
  __shared__ unsigned int h0[256], h1[256];
  __shared__ unsigned int sT;
  __shared__ unsigned int candCount;
  __shared__ unsigned long long cand[kCandMax];
  int tid = threadIdx.x;
  if (tid < 256) { h0[tid] = P.ghist0[bl * 256 + tid]; h1[tid] = P.ghist1[bl * 256 + tid]; }
  if (tid == 0) candCount = 0u;
  __syncthreads();
  if (tid == 0) {
    unsigned int kk = (unsigned int)K, cum = 0;
    int v0 = 255;
    for (; v0 > 0; --v0) { unsigned int x = h0[v0]; if (cum + x >= kk) break; cum += x; }
    kk -= cum;
    unsigned int cum1 = 0; int v1 = 255;
    for (; v1 > 0; --v1) { unsigned int x = h1[v1]; if (cum1 + x >= kk) break; cum1 += x; }
    sT = ((((unsigned int)v0) << 8) | (unsigned int)v1) << 16;
  }
  __syncthreads();
  unsigned int T = sT;
  // compact all elements with key >= T (superset of the top-K incl. ties)
  for (int i = tid; i < N; i += 1024) {
    unsigned int u = fkey(ctr[i]);
    if (u >= T) {
      unsigned int p = atomicAdd(&candCount, 1u);
      if (p < (unsigned int)kCandMax)
        cand[p] = ((unsigned long long)u << 32) |
                  (unsigned long long)(0xFFFFFFFFu - (unsigned int)i);
    }
  }
  __syncthreads();
  int cc = (int)candCount; if (cc > kCandMax) cc = kCandMax;
  int n2 = 1; while (n2 < cc) n2 <<= 1;
  for (int i = cc + tid; i < n2; i += 1024) cand[i] = 0ull;
  __syncthreads();
  // bitonic sort descending by (key desc, idx asc) composite
  for (int size = 2; size <= n2; size <<= 1) {
    for (int stride = size >> 1; stride > 0; stride >>= 1) {
      for (int i = tid; i < n2; i += 1024) {
        int j = i ^ stride;
        if (j > i) {
          unsigned long long a = cand[i], c2 = cand[j];
          bool sw = ((i & size) == 0) ? (a < c2) : (a > c2);
          if (sw) { cand[i] = c2; cand[j] = a; }
        }
      }
      __syncthreads();
    }
  }
  size_t sbase = ((size_t)b * 5 + l) * 1024;
  for (int r = tid; r < K; r += 1024) {
    unsigned long long cv = cand[r];
    unsigned int idx = 0xFFFFFFFFu - (unsigned int)(cv & 0xFFFFFFFFu);
    float s = ctr[idx];
    float4 anc = *(const float4*)(P.anchors[l] + (size_t)idx * 4);
    float4 dd  = *(const float4*)(P.deltas[l] + ((size_t)b * N + idx) * 4);
    // Box2BoxTransformLinear decode (same op order as reference, no fma)
    float w = anc.z - anc.x, hgt = anc.w - anc.y;
    float cx = (anc.x + anc.z) * 0.5f, cy = (anc.y + anc.w) * 0.5f;
    float x1 = cx - dd.x * w;
    float y1 = cy - dd.y * hgt;
    float x2 = cx + dd.z * w;
    float y2 = cy + dd.w * hgt;
    x1 = fminf(fmaxf(x1, 0.0f), 1024.0f);
    y1 = fminf(fmaxf(y1, 0.0f), 1024.0f);
    x2 = fminf(fmaxf(x2, 0.0f), 1024.0f);
    y2 = fminf(fmaxf(y2, 0.0f), 1024.0f);
    bool valid = ((x2 - x1) > 0.0f) && ((y2 - y1) > 0.0f);
    P.scores[sbase + r] = valid ? s : -INFINITY;
    *(float4*)(P.boxes + (sbase + r) * 4) = make_float4(x1, y1, x2, y2);
  }
}

// ---------------- Phase 2a: suppression bitmask (per level) ---------------
__global__ __launch_bounds__(256) void k_mask(RPNParams P) {
  int bl = blockIdx.x, b = bl / 5, l = bl % 5;
  int c = blockIdx.y;  // row-class i % 8 == c
  int K = c_K[l];
  float off = (float)l * 1025.0f;  // lvl * (IMG + 1) — replicate offset rounding!
  size_t sbase = ((size_t)b * 5 + l) * 1024;
  __shared__ float4 obox[1024];
  __shared__ float oarea[1024];
  int tid = threadIdx.x;
  for (int i = tid; i < K; i += 256) {
    float4 v = ((const float4*)P.boxes)[sbase + i];
    v.x += off; v.y += off; v.z += off; v.w += off;
    obox[i] = v;
    oarea[i] = fmaxf(v.z - v.x, 0.0f) * fmaxf(v.w - v.y, 0.0f);
  }
  __syncthreads();
  unsigned int* mrow = P.mask + sbase * 32;
  for (int it = tid; it < 128 * 32; it += 256) {
    int ri = it >> 5, wj = it & 31;
    int i = c + ri * 8;
    if (i >= K) continue;
    float4 bi = obox[i]; float ai = oarea[i];
    unsigned int bits = 0u;
    int j0 = wj * 32;
    if (j0 + 31 > i) {
      for (int jj = 0; jj < 32; ++jj) {
        int j = j0 + jj;
        if (j > i && j < K) {
          float4 bj = obox[j];
          float xx1 = fmaxf(bi.x, bj.x);
          float yy1 = fmaxf(bi.y, bj.y);
          float xx2 = fminf(bi.z, bj.z);
          float yy2 = fminf(bi.w, bj.w);
          float ww = fmaxf(xx2 - xx1, 0.0f);
          float hh = fmaxf(yy2 - yy1, 0.0f);
          float inter = ww * hh;
          float uni = ai + oarea[j] - inter + 1e-8f;  // ((ai+aj)-inter)+eps
          if (inter / uni > 0.7f) bits |= (1u << jj);
        }
      }
    }
    mrow[(size_t)i * 32 + wj] = bits;
  }
}

// ---------------- Phase 2b: serial greedy sweep (1 wave / (img,lvl)) ------
__global__ __launch_bounds__(1024) void k_sweep(RPNParams P) {
  int bl = blockIdx.x, b = bl / 5, l = bl % 5;
  int K = c_K[l];
  size_t sbase = ((size_t)b * 5 + l) * 1024;
  __shared__ unsigned long long lmask[16 * 1000];  // 125 KiB
  int tid = threadIdx.x;
  const unsigned long long* gm = (const unsigned long long*)(P.mask + sbase * 32);
  for (int i = tid; i < K * 16; i += 1024) lmask[i] = gm[i];
  __syncthreads();
  if (tid < 64) {
    int lane = tid;
    unsigned long long kw = 0ull;  // lanes 0..15 hold keep words
    for (int g = 0; g < 16; ++g) {
      int e = g * 64 + lane;
      bool pred = (e < K) && (P.scores[sbase + e] > -INFINITY);
      unsigned long long m = __ballot(pred);
      if (lane == g) kw = m;
    }
    for (int i = 0; i < K; ++i) {
      unsigned long long w64 = shfl64(kw, i >> 6);
      if ((w64 >> (i & 63)) & 1ull) {
        kw &= ~lmask[i * 16 + (lane & 15)];
      }
    }
    for (int g = 0; g < 16; ++g) {
      unsigned long long w64 = shfl64(kw, g);
      int e = g * 64 + lane;
      if (e < K) P.keep[sbase + e] = (unsigned char)((w64 >> lane) & 1ull);
    }
  }
}

// ------- Phase 3: per-image global sort + stable keep-partition + out -----
__global__ __launch_bounds__(1024) void k_merge(RPNParams P) {
  int b = blockIdx.x;
  __shared__ unsigned long long key[8192];  // 64 KiB
  __shared__ unsigned int tsum[1024];
  __shared__ unsigned int wsum[16];
  __shared__ unsigned int sTot;
  int tid = threadIdx.x;
  for (int i = tid; i < 8192; i += 1024) {
    unsigned long long kv = 0ull;
    if (i < 4768) {
      int l = (i >= 4000) ? 4 : (i / 1000);
      int r = i - l * 1000;
      float s = P.scores[((size_t)b * 5 + l) * 1024 + r];
      kv = ((unsigned long long)fkey(s) << 32) |
           (unsigned long long)(0xFFFFFFFFu - (unsigned int)i);
    }
    key[i] = kv;
  }
  __syncthreads();
  for (int size = 2; size <= 8192; size <<= 1) {
    for (int stride = size >> 1; stride > 0; stride >>= 1) {
      for (int i = tid; i < 8192; i += 1024) {
        int j = i ^ stride;
        if (j > i) {
          unsigned long long a = key[i], c2 = key[j];
          bool sw = ((i & size) == 0) ? (a < c2) : (a > c2);
          if (sw) { key[i] = c2; key[j] = a; }
        }
      }
      __syncthreads();
    }
  }
  // keep flags for this thread's 8 contiguous sorted slots
  int base = tid * 8;
  unsigned char lf[8];
  unsigned int lsum = 0;
  for (int q = 0; q < 8; ++q) {
    int i = base + q;
    unsigned char f = 0;
    if (i < 4768) {
      unsigned int cidx = 0xFFFFFFFFu - (unsigned int)(key[i] & 0xFFFFFFFFu);
      int l = (cidx >= 4000u) ? 4 : (int)(cidx / 1000u);
      int r = (int)cidx - l * 1000;
      f = P.keep[((size_t)b * 5 + l) * 1024 + r];
    }
    lf[q] = f; lsum += f;
  }
  tsum[tid] = lsum;
  __syncthreads();
  int lane = tid & 63, wid = tid >> 6;
  unsigned int v = lsum;
  for (int d = 1; d < 64; d <<= 1) {
    unsigned int n = __shfl_up(v, (unsigned int)d, 64);
    if (lane >= d) v += n;
  }
  if (lane == 63) wsum[wid] = v;
  __syncthreads();
  if (tid == 0) {
    unsigned int acc = 0;
    for (int w = 0; w < 16; ++w) { unsigned int x = wsum[w]; wsum[w] = acc; acc += x; }
    sTot = acc;
  }
  __syncthreads();
  unsigned int excl = wsum[wid] + (v - lsum);  // kept count before slot `base`
  unsigned int tot = sTot;
  for (int q = 0; q < 8; ++q) {
    int i = base + q;
    if (i >= 4768) break;
    unsigned int cidx = 0xFFFFFFFFu - (unsigned int)(key[i] & 0xFFFFFFFFu);
    int l = (cidx >= 4000u) ? 4 : (int)(cidx / 1000u);
    int r = (int)cidx - l * 1000;
    size_t sb = ((size_t)b * 5 + l) * 1024 + r;
    unsigned char f = lf[q];
    unsigned int pos = f ? excl : (tot + ((unsigned int)i - excl));
    excl += f;
    if (pos < 1000u) {
      float4 bx = ((const float4*)P.boxes)[sb];
      float sc = f ? P.scores[sb] : -INFINITY;
      float* o = P.out + ((size_t)b * 1000 + pos) * 5;
      o[0] = bx.x; o[1] = bx.y; o[2] = bx.z; o[3] = bx.w; o[4] = sc;
    }
  }
}

}  // namespace

extern "C" void kernel_launch(void* const* d_in, const int* in_sizes, int n_in,
                              void* d_out, int out_size, void* d_ws, size_t ws_size,
                              hipStream_t stream) {
  (void)out_size; (void)ws_size;
  RPNParams P;
  // setup_inputs() dict order is interleaved (deltas,ctr,anchors per level);
  // detect by anchors_p2 size in slot 2 in case the harness grouped by arg.
  bool interleaved = (n_in >= 3) && (in_sizes[2] == 786432);
  for (int l = 0; l < 5; ++l) {
    if (interleaved) {
      P.deltas[l]  = (const float*)d_in[3 * l + 0];
      P.ctr[l]     = (const float*)d_in[3 * l + 1];
      P.anchors[l] = (const float*)d_in[3 * l + 2];
    } else {
      P.deltas[l]  = (const float*)d_in[l];
      P.ctr[l]     = (const float*)d_in[5 + l];
      P.anchors[l] = (const float*)d_in[10 + l];
    }
  }
  char* ws = (char*)d_ws;
  P.scores = (float*)(ws + 0);               // 163840 B
  P.boxes  = (float*)(ws + 163840);          // 655360 B
  P.keep   = (unsigned char*)(ws + 819200);  // 40960 B
  P.mask   = (unsigned int*)(ws + 860160);   // 5242880 B
  P.ghist0 = (unsigned int*)(ws + 6103040);  // 40960 B
  P.ghist1 = (unsigned int*)(ws + 6144000);  // 40960 B
  P.out    = (float*)d_out;

  hipMemsetAsync(ws + 6103040, 0, 81920, stream);  // zero both histograms
  hipLaunchKernelGGL(k_hist0, dim3(40, 32), dim3(256), 0, stream, P);
  hipLaunchKernelGGL(k_hist1, dim3(40, 32), dim3(256), 0, stream, P);
  hipLaunchKernelGGL(k_select, dim3(40), dim3(1024), 0, stream, P);
  hipLaunchKernelGGL(k_mask, dim3(40, 8), dim3(256), 0, stream, P);
  hipLaunchKernelGGL(k_sweep, dim3(40), dim3(1024), 0, stream, P);
  hipLaunchKernelGGL(k_merge, dim3(8), dim3(1024), 0, stream, P);
}

// Round 2
// 376.268 us; speedup vs baseline: 1.2286x; 1.2286x over previous
//
#include <hip/hip_runtime.h>
#include <cstdint>
#include <cstddef>
#include <cmath>

#pragma clang fp contract(off)

namespace {

constexpr int kCandMax = 4096;

__device__ __constant__ int c_N[5] = {196608, 49152, 12288, 3072, 768};
__device__ __constant__ int c_K[5] = {1000, 1000, 1000, 1000, 768};

struct RPNParams {
  const float* deltas[5];
  const float* ctr[5];
  const float* anchors[5];
  float* scores;         // [8][5][1024] masked scores, per-level sorted desc
  float* boxes;          // [8][5][1024][4] clipped boxes, per-level sorted
  unsigned char* keep;   // [8][5][1024]
  unsigned int* mask;    // [8][5][1024][32] suppression bits (j in bits, row i)
  unsigned int* ghist0;  // [40][256]
  unsigned int* ghist1;  // [40][256]
  float* out;            // [8][1000][5]
};

// monotonic float->uint map (larger float => larger uint)
__device__ __forceinline__ unsigned int fkey(float f) {
  unsigned int u = __float_as_uint(f);
  return (u & 0x80000000u) ? ~u : (u | 0x80000000u);
}

__device__ __forceinline__ unsigned long long shfl64(unsigned long long v, int src) {
  unsigned int lo = __shfl((unsigned int)(v & 0xFFFFFFFFu), src, 64);
  unsigned int hi = __shfl((unsigned int)(v >> 32), src, 64);
  return ((unsigned long long)hi << 32) | (unsigned long long)lo;
}

// ---------------- Phase 1a: 8-bit histogram of score keys ----------------
__global__ __launch_bounds__(256) void k_hist0(RPNParams P) {
  int bl = blockIdx.x, b = bl / 5, l = bl % 5;
  int N = c_N[l];
  int chunk = (N + 31) / 32;
  int i0 = blockIdx.y * chunk;
  int i1 = i0 + chunk; if (i1 > N) i1 = N;
  const float* ctr = P.ctr[l] + (size_t)b * N;
  __shared__ unsigned int wh[4][256];
  int tid = threadIdx.x, wid = tid >> 6;
  for (int i = tid; i < 1024; i += 256) ((unsigned int*)wh)[i] = 0u;
  __syncthreads();
  for (int i = i0 + tid; i < i1; i += 256) {
    unsigned int u = fkey(ctr[i]);
    atomicAdd(&wh[wid][u >> 24], 1u);
  }
  __syncthreads();
  int bin = tid;
  unsigned int s = wh[0][bin] + wh[1][bin] + wh[2][bin] + wh[3][bin];
  if (s) atomicAdd(&P.ghist0[bl * 256 + bin], s);
}

// ---------------- Phase 1b: refine to 16-bit within chosen top byte ------
__global__ __launch_bounds__(256) void k_hist1(RPNParams P) {
  int bl = blockIdx.x, b = bl / 5, l = bl % 5;
  int N = c_N[l], K = c_K[l];
  int chunk = (N + 31) / 32;
  int i0 = blockIdx.y * chunk;
  int i1 = i0 + chunk; if (i1 > N) i1 = N;
  const float* ctr = P.ctr[l] + (size_t)b * N;
  __shared__ unsigned int wh[4][256];
  __shared__ unsigned int sV0;
  int tid = threadIdx.x, wid = tid >> 6;
  if (tid < 256) wh[0][tid] = P.ghist0[bl * 256 + tid];
  __syncthreads();
  if (tid == 0) {
    unsigned int kk = (unsigned int)K, cum = 0;
    int v = 255;
    for (; v > 0; --v) { unsigned int x = wh[0][v]; if (cum + x >= kk) break; cum += x; }
    sV0 = (unsigned int)v;
  }
  __syncthreads();
  unsigned int v0 = sV0;
  for (int i = tid; i < 1024; i += 256) ((unsigned int*)wh)[i] = 0u;
  __syncthreads();
  for (int i = i0 + tid; i < i1; i += 256) {
    unsigned int u = fkey(ctr[i]);
    if ((u >> 24) == v0) atomicAdd(&wh[wid][(u >> 16) & 255u], 1u);
  }
  __syncthreads();
  int bin = tid;
  unsigned int s = wh[0][bin] + wh[1][bin] + wh[2][bin] + wh[3][bin];
  if (s) atomicAdd(&P.ghist1[bl * 256 + bin], s);
}

// ---- Phase 1c: threshold, compact candidates, sort, decode+clip boxes ----
__global__ __launch_bounds__(1024) void k_select(RPNParams P) {
  int bl = blockIdx.x, b = bl / 5, l = bl % 5;
  int N = c_N[l], K = c_K[l];
  const float* ctr = P.ctr[l] + (size_t)b * N;
  __shared__ unsigned int h0[256], h1[256];
  __shared__ unsigned int sT;
  __shared__ unsigned int candCount;
  __shared__ unsigned long long cand[kCandMax];
  int tid = threadIdx.x;
  if (tid < 256) { h0[tid] = P.ghist0[bl * 256 + tid]; h1[tid] = P.ghist1[bl * 256 + tid]; }
  if (tid == 0) candCount = 0u;
  __syncthreads();
  if (tid == 0) {
    unsigned int kk = (unsigned int)K, cum = 0;
    int v0 = 255;
    for (; v0 > 0; --v0) { unsigned int x = h0[v0]; if (cum + x >= kk) break; cum += x; }
    kk -= cum;
    unsigned int cum1 = 0; int v1 = 255;
    for (; v1 > 0; --v1) { unsigned int x = h1[v1]; if (cum1 + x >= kk) break; cum1 += x; }
    sT = ((((unsigned int)v0) << 8) | (unsigned int)v1) << 16;
  }
  __syncthreads();
  unsigned int T = sT;
  // compact all elements with key >= T (superset of the top-K incl. ties)
  for (int i = tid; i < N; i += 1024) {
    unsigned int u = fkey(ctr[i]);
    if (u >= T) {
      unsigned int p = atomicAdd(&candCount, 1u);
      if (p < (unsigned int)kCandMax)
        cand[p] = ((unsigned long long)u << 32) |
                  (unsigned long long)(0xFFFFFFFFu - (unsigned int)i);
    }
  }
  __syncthreads();
  int cc = (int)candCount; if (cc > kCandMax) cc = kCandMax;
  int n2 = 1; while (n2 < cc) n2 <<= 1;
  for (int i = cc + tid; i < n2; i += 1024) cand[i] = 0ull;
  __syncthreads();
  // bitonic sort descending by (key desc, idx asc) composite
  for (int size = 2; size <= n2; size <<= 1) {
    for (int stride = size >> 1; stride > 0; stride >>= 1) {
      for (int i = tid; i < n2; i += 1024) {
        int j = i ^ stride;
        if (j > i) {
          unsigned long long a = cand[i], c2 = cand[j];
          bool sw = ((i & size) == 0) ? (a < c2) : (a > c2);
          if (sw) { cand[i] = c2; cand[j] = a; }
        }
      }
      __syncthreads();
    }
  }
  size_t sbase = ((size_t)b * 5 + l) * 1024;
  for (int r = tid; r < K; r += 1024) {
    unsigned long long cv = cand[r];
    unsigned int idx = 0xFFFFFFFFu - (unsigned int)(cv & 0xFFFFFFFFu);
    float s = ctr[idx];
    float4 anc = *(const float4*)(P.anchors[l] + (size_t)idx * 4);
    float4 dd  = *(const float4*)(P.deltas[l] + ((size_t)b * N + idx) * 4);
    // Box2BoxTransformLinear decode (same op order as reference, no fma)
    float w = anc.z - anc.x, hgt = anc.w - anc.y;
    float cx = (anc.x + anc.z) * 0.5f, cy = (anc.y + anc.w) * 0.5f;
    float x1 = cx - dd.x * w;
    float y1 = cy - dd.y * hgt;
    float x2 = cx + dd.z * w;
    float y2 = cy + dd.w * hgt;
    x1 = fminf(fmaxf(x1, 0.0f), 1024.0f);
    y1 = fminf(fmaxf(y1, 0.0f), 1024.0f);
    x2 = fminf(fmaxf(x2, 0.0f), 1024.0f);
    y2 = fminf(fmaxf(y2, 0.0f), 1024.0f);
    bool valid = ((x2 - x1) > 0.0f) && ((y2 - y1) > 0.0f);
    P.scores[sbase + r] = valid ? s : -INFINITY;
    *(float4*)(P.boxes + (sbase + r) * 4) = make_float4(x1, y1, x2, y2);
  }
}

// ---------------- Phase 2a: suppression bitmask (per level) ---------------
// One lane per row i; all lanes sweep the same j together -> every LDS read
// of box j is a same-address broadcast (zero bank conflicts). Boxes stored
// SoA, zero-padded to 1024 so no j<K guard is needed (pad IoU == 0).
// Grid: (40 pairs, 16 row-groups of 64, 2 column-halves). Word range per
// row-group is wave-uniform; triangular skip via w0 = first word with j > min row.
__global__ __launch_bounds__(64) void k_mask(RPNParams P) {
  int bl = blockIdx.x, b = bl / 5, l = bl % 5;
  int K = c_K[l];
  int yg = blockIdx.y;   // rows yg*64 .. yg*64+63
  int zc = blockIdx.z;   // column half
  float off = (float)l * 1025.0f;  // lvl * (IMG + 1) — replicate offset rounding!
  size_t sbase = ((size_t)b * 5 + l) * 1024;
  __shared__ float bx1[1024], by1[1024], bx2[1024], by2[1024], barea[1024];
  int tid = threadIdx.x;
  for (int i = tid; i < 1024; i += 64) {
    float4 v = make_float4(0.f, 0.f, 0.f, 0.f);
    if (i < K) {
      v = ((const float4*)P.boxes)[sbase + i];
      v.x += off; v.y += off; v.z += off; v.w += off;
    }
    bx1[i] = v.x; by1[i] = v.y; bx2[i] = v.z; by2[i] = v.w;
    barea[i] = fmaxf(v.z - v.x, 0.0f) * fmaxf(v.w - v.y, 0.0f);
  }
  __syncthreads();
  int i = yg * 64 + tid;
  if (i >= K) return;  // (after the barrier; no further barriers below)
  float x1 = bx1[i], y1 = by1[i], x2 = bx2[i], y2 = by2[i], ai = barea[i];
  unsigned int* mrow = P.mask + (sbase + (size_t)i) * 32;
  int w0 = (yg * 64 + 1) >> 5;      // wave-uniform first word with any j > row
  int nw = 32 - w0;
  int half0 = (nw + 1) >> 1;
  int wbeg = (zc == 0) ? w0 : (w0 + half0);
  int wend = (zc == 0) ? (w0 + half0) : 32;
  if (zc == 0)
    for (int w = 0; w < w0; ++w) mrow[w] = 0u;  // low words: all j <= min row
  for (int w = wbeg; w < wend; ++w) {
    unsigned int bits = 0u;
    int j0 = w << 5;
    for (int jj = 0; jj < 32; ++jj) {
      int j = j0 + jj;
      float xx1 = fmaxf(x1, bx1[j]);
      float yy1 = fmaxf(y1, by1[j]);
      float xx2 = fminf(x2, bx2[j]);
      float yy2 = fminf(y2, by2[j]);
      float ww = fmaxf(xx2 - xx1, 0.0f);
      float hh = fmaxf(yy2 - yy1, 0.0f);
      float inter = ww * hh;
      float uni = ai + barea[j] - inter + 1e-8f;  // ((ai+aj)-inter)+eps
      if ((inter / uni > 0.7f) && (j > i)) bits |= (1u << jj);
    }
    mrow[w] = bits;
  }
}

// ---------------- Phase 2b: serial greedy sweep (1 wave / (img,lvl)) ------
__global__ __launch_bounds__(1024) void k_sweep(RPNParams P) {
  int bl = blockIdx.x, b = bl / 5, l = bl % 5;
  int K = c_K[l];
  size_t sbase = ((size_t)b * 5 + l) * 1024;
  __shared__ unsigned long long lmask[16 * 1000];  // 125 KiB
  int tid = threadIdx.x;
  const unsigned long long* gm = (const unsigned long long*)(P.mask + sbase * 32);
  for (int i = tid; i < K * 16; i += 1024) lmask[i] = gm[i];
  __syncthreads();
  if (tid < 64) {
    int lane = tid;
    unsigned long long kw = 0ull;  // lanes 0..15 hold keep words
    for (int g = 0; g < 16; ++g) {
      int e = g * 64 + lane;
      bool pred = (e < K) && (P.scores[sbase + e] > -INFINITY);
      unsigned long long m = __ballot(pred);
      if (lane == g) kw = m;
    }
    for (int i = 0; i < K; ++i) {
      unsigned long long w64 = shfl64(kw, i >> 6);
      if ((w64 >> (i & 63)) & 1ull) {
        kw &= ~lmask[i * 16 + (lane & 15)];
      }
    }
    for (int g = 0; g < 16; ++g) {
      unsigned long long w64 = shfl64(kw, g);
      int e = g * 64 + lane;
      if (e < K) P.keep[sbase + e] = (unsigned char)((w64 >> lane) & 1ull);
    }
  }
}

// ------- Phase 3: per-image global sort + stable keep-partition + out -----
__global__ __launch_bounds__(1024) void k_merge(RPNParams P) {
  int b = blockIdx.x;
  __shared__ unsigned long long key[8192];  // 64 KiB
  __shared__ unsigned int tsum[1024];
  __shared__ unsigned int wsum[16];
  __shared__ unsigned int sTot;
  int tid = threadIdx.x;
  for (int i = tid; i < 8192; i += 1024) {
    unsigned long long kv = 0ull;
    if (i < 4768) {
      int l = (i >= 4000) ? 4 : (i / 1000);
      int r = i - l * 1000;
      float s = P.scores[((size_t)b * 5 + l) * 1024 + r];
      kv = ((unsigned long long)fkey(s) << 32) |
           (unsigned long long)(0xFFFFFFFFu - (unsigned int)i);
    }
    key[i] = kv;
  }
  __syncthreads();
  for (int size = 2; size <= 8192; size <<= 1) {
    for (int stride = size >> 1; stride > 0; stride >>= 1) {
      for (int i = tid; i < 8192; i += 1024) {
        int j = i ^ stride;
        if (j > i) {
          unsigned long long a = key[i], c2 = key[j];
          bool sw = ((i & size) == 0) ? (a < c2) : (a > c2);
          if (sw) { key[i] = c2; key[j] = a; }
        }
      }
      __syncthreads();
    }
  }
  // keep flags for this thread's 8 contiguous sorted slots
  int base = tid * 8;
  unsigned char lf[8];
  unsigned int lsum = 0;
  for (int q = 0; q < 8; ++q) {
    int i = base + q;
    unsigned char f = 0;
    if (i < 4768) {
      unsigned int cidx = 0xFFFFFFFFu - (unsigned int)(key[i] & 0xFFFFFFFFu);
      int l = (cidx >= 4000u) ? 4 : (int)(cidx / 1000u);
      int r = (int)cidx - l * 1000;
      f = P.keep[((size_t)b * 5 + l) * 1024 + r];
    }
    lf[q] = f; lsum += f;
  }
  tsum[tid] = lsum;
  __syncthreads();
  int lane = tid & 63, wid = tid >> 6;
  unsigned int v = lsum;
  for (int d = 1; d < 64; d <<= 1) {
    unsigned int n = __shfl_up(v, (unsigned int)d, 64);
    if (lane >= d) v += n;
  }
  if (lane == 63) wsum[wid] = v;
  __syncthreads();
  if (tid == 0) {
    unsigned int acc = 0;
    for (int w = 0; w < 16; ++w) { unsigned int x = wsum[w]; wsum[w] = acc; acc += x; }
    sTot = acc;
  }
  __syncthreads();
  unsigned int excl = wsum[wid] + (v - lsum);  // kept count before slot `base`
  unsigned int tot = sTot;
  for (int q = 0; q < 8; ++q) {
    int i = base + q;
    if (i >= 4768) break;
    unsigned int cidx = 0xFFFFFFFFu - (unsigned int)(key[i] & 0xFFFFFFFFu);
    int l = (cidx >= 4000u) ? 4 : (int)(cidx / 1000u);
    int r = (int)cidx - l * 1000;
    size_t sb = ((size_t)b * 5 + l) * 1024 + r;
    unsigned char f = lf[q];
    unsigned int pos = f ? excl : (tot + ((unsigned int)i - excl));
    excl += f;
    if (pos < 1000u) {
      float4 bx = ((const float4*)P.boxes)[sb];
      float sc = f ? P.scores[sb] : -INFINITY;
      float* o = P.out + ((size_t)b * 1000 + pos) * 5;
      o[0] = bx.x; o[1] = bx.y; o[2] = bx.z; o[3] = bx.w; o[4] = sc;
    }
  }
}

}  // namespace

extern "C" void kernel_launch(void* const* d_in, const int* in_sizes, int n_in,
                              void* d_out, int out_size, void* d_ws, size_t ws_size,
                              hipStream_t stream) {
  (void)out_size; (void)ws_size;
  RPNParams P;
  // setup_inputs() dict order is interleaved (deltas,ctr,anchors per level);
  // detect by anchors_p2 size in slot 2 in case the harness grouped by arg.
  bool interleaved = (n_in >= 3) && (in_sizes[2] == 786432);
  for (int l = 0; l < 5; ++l) {
    if (interleaved) {
      P.deltas[l]  = (const float*)d_in[3 * l + 0];
      P.ctr[l]     = (const float*)d_in[3 * l + 1];
      P.anchors[l] = (const float*)d_in[3 * l + 2];
    } else {
      P.deltas[l]  = (const float*)d_in[l];
      P.ctr[l]     = (const float*)d_in[5 + l];
      P.anchors[l] = (const float*)d_in[10 + l];
    }
  }
  char* ws = (char*)d_ws;
  P.scores = (float*)(ws + 0);               // 163840 B
  P.boxes  = (float*)(ws + 163840);          // 655360 B
  P.keep   = (unsigned char*)(ws + 819200);  // 40960 B
  P.mask   = (unsigned int*)(ws + 860160);   // 5242880 B
  P.ghist0 = (unsigned int*)(ws + 6103040);  // 40960 B
  P.ghist1 = (unsigned int*)(ws + 6144000);  // 40960 B
  P.out    = (float*)d_out;

  hipMemsetAsync(ws + 6103040, 0, 81920, stream);  // zero both histograms
  hipLaunchKernelGGL(k_hist0, dim3(40, 32), dim3(256), 0, stream, P);
  hipLaunchKernelGGL(k_hist1, dim3(40, 32), dim3(256), 0, stream, P);
  hipLaunchKernelGGL(k_select, dim3(40), dim3(1024), 0, stream, P);
  hipLaunchKernelGGL(k_mask, dim3(40, 16, 2), dim3(64), 0, stream, P);
  hipLaunchKernelGGL(k_sweep, dim3(40), dim3(1024), 0, stream, P);
  hipLaunchKernelGGL(k_merge, dim3(8), dim3(1024), 0, stream, P);
}

// Round 3
// 278.542 us; speedup vs baseline: 1.6597x; 1.3508x over previous
//
#include <hip/hip_runtime.h>
#include <cstdint>
#include <cstddef>
#include <cmath>

#pragma clang fp contract(off)

namespace {

constexpr int kCandMax = 4096;

__device__ __constant__ int c_N[5] = {196608, 49152, 12288, 3072, 768};
__device__ __constant__ int c_K[5] = {1000, 1000, 1000, 1000, 768};

struct RPNParams {
  const float* deltas[5];
  const float* ctr[5];
  const float* anchors[5];
  float* scores;         // [8][5][1024] masked scores, per-level sorted desc
  float* boxes;          // [8][5][1024][4] clipped boxes, per-level sorted
  unsigned char* keep;   // [8][5][1024]
  unsigned int* mask;    // [8][5][1024][32] suppression bits (j in bits, row i)
  unsigned int* ghist0;  // [40][256]
  unsigned int* ghist1;  // [40][256]
  float* out;            // [8][1000][5]
};

// monotonic float->uint map (larger float => larger uint)
__device__ __forceinline__ unsigned int fkey(float f) {
  unsigned int u = __float_as_uint(f);
  return (u & 0x80000000u) ? ~u : (u | 0x80000000u);
}

__device__ __forceinline__ unsigned long long shfl64(unsigned long long v, int src) {
  unsigned int lo = __shfl((unsigned int)(v & 0xFFFFFFFFu), src, 64);
  unsigned int hi = __shfl((unsigned int)(v >> 32), src, 64);
  return ((unsigned long long)hi << 32) | (unsigned long long)lo;
}

// ---------------- Phase 1a: 8-bit histogram of score keys ----------------
__global__ __launch_bounds__(256) void k_hist0(RPNParams P) {
  int bl = blockIdx.x, b = bl / 5, l = bl % 5;
  int N = c_N[l];
  int chunk = (N + 31) / 32;
  int i0 = blockIdx.y * chunk;
  int i1 = i0 + chunk; if (i1 > N) i1 = N;
  const float* ctr = P.ctr[l] + (size_t)b * N;
  __shared__ unsigned int wh[4][256];
  int tid = threadIdx.x, wid = tid >> 6;
  for (int i = tid; i < 1024; i += 256) ((unsigned int*)wh)[i] = 0u;
  __syncthreads();
  for (int i = i0 + tid; i < i1; i += 256) {
    unsigned int u = fkey(ctr[i]);
    atomicAdd(&wh[wid][u >> 24], 1u);
  }
  __syncthreads();
  int bin = tid;
  unsigned int s = wh[0][bin] + wh[1][bin] + wh[2][bin] + wh[3][bin];
  if (s) atomicAdd(&P.ghist0[bl * 256 + bin], s);
}

// ---------------- Phase 1b: refine to 16-bit within chosen top byte ------
__global__ __launch_bounds__(256) void k_hist1(RPNParams P) {
  int bl = blockIdx.x, b = bl / 5, l = bl % 5;
  int N = c_N[l], K = c_K[l];
  int chunk = (N + 31) / 32;
  int i0 = blockIdx.y * chunk;
  int i1 = i0 + chunk; if (i1 > N) i1 = N;
  const float* ctr = P.ctr[l] + (size_t)b * N;
  __shared__ unsigned int wh[4][256];
  __shared__ unsigned int sV0;
  int tid = threadIdx.x, wid = tid >> 6;
  if (tid < 256) wh[0][tid] = P.ghist0[bl * 256 + tid];
  __syncthreads();
  if (tid == 0) {
    unsigned int kk = (unsigned int)K, cum = 0;
    int v = 255;
    for (; v > 0; --v) { unsigned int x = wh[0][v]; if (cum + x >= kk) break; cum += x; }
    sV0 = (unsigned int)v;
  }
  __syncthreads();
  unsigned int v0 = sV0;
  for (int i = tid; i < 1024; i += 256) ((unsigned int*)wh)[i] = 0u;
  __syncthreads();
  for (int i = i0 + tid; i < i1; i += 256) {
    unsigned int u = fkey(ctr[i]);
    if ((u >> 24) == v0) atomicAdd(&wh[wid][(u >> 16) & 255u], 1u);
  }
  __syncthreads();
  int bin = tid;
  unsigned int s = wh[0][bin] + wh[1][bin] + wh[2][bin] + wh[3][bin];
  if (s) atomicAdd(&P.ghist1[bl * 256 + bin], s);
}

// ---- Phase 1c: threshold, compact candidates, sort, decode+clip boxes ----
__global__ __launch_bounds__(1024) void k_select(RPNParams P) {
  int bl = blockIdx.x, b = bl / 5, l = bl % 5;
  int N = c_N[l], K = c_K[l];
  const float* ctr = P.ctr[l] + (size_t)b * N;
  __shared__ unsigned int h0[256], h1[256];
  __shared__ unsigned int sT;
  __shared__ unsigned int candCount;
  __shared__ unsigned long long cand[kCandMax];
  int tid = threadIdx.x;
  if (tid < 256) { h0[tid] = P.ghist0[bl * 256 + tid]; h1[tid] = P.ghist1[bl * 256 + tid]; }
  if (tid == 0) candCount = 0u;
  __syncthreads();
  if (tid == 0) {
    unsigned int kk = (unsigned int)K, cum = 0;
    int v0 = 255;
    for (; v0 > 0; --v0) { unsigned int x = h0[v0]; if (cum + x >= kk) break; cum += x; }
    kk -= cum;
    unsigned int cum1 = 0; int v1 = 255;
    for (; v1 > 0; --v1) { unsigned int x = h1[v1]; if (cum1 + x >= kk) break; cum1 += x; }
    sT = ((((unsigned int)v0) << 8) | (unsigned int)v1) << 16;
  }
  __syncthreads();
  unsigned int T = sT;
  // compact all elements with key >= T (superset of the top-K incl. ties)
  for (int i = tid; i < N; i += 1024) {
    unsigned int u = fkey(ctr[i]);
    if (u >= T) {
      unsigned int p = atomicAdd(&candCount, 1u);
      if (p < (unsigned int)kCandMax)
        cand[p] = ((unsigned long long)u << 32) |
                  (unsigned long long)(0xFFFFFFFFu - (unsigned int)i);
    }
  }
  __syncthreads();
  int cc = (int)candCount; if (cc > kCandMax) cc = kCandMax;
  int n2 = 1; while (n2 < cc) n2 <<= 1;
  for (int i = cc + tid; i < n2; i += 1024) cand[i] = 0ull;
  __syncthreads();
  // bitonic sort descending by (key desc, idx asc) composite
  for (int size = 2; size <= n2; size <<= 1) {
    for (int stride = size >> 1; stride > 0; stride >>= 1) {
      for (int i = tid; i < n2; i += 1024) {
        int j = i ^ stride;
        if (j > i) {
          unsigned long long a = cand[i], c2 = cand[j];
          bool sw = ((i & size) == 0) ? (a < c2) : (a > c2);
          if (sw) { cand[i] = c2; cand[j] = a; }
        }
      }
      __syncthreads();
    }
  }
  size_t sbase = ((size_t)b * 5 + l) * 1024;
  for (int r = tid; r < K; r += 1024) {
    unsigned long long cv = cand[r];
    unsigned int idx = 0xFFFFFFFFu - (unsigned int)(cv & 0xFFFFFFFFu);
    float s = ctr[idx];
    float4 anc = *(const float4*)(P.anchors[l] + (size_t)idx * 4);
    float4 dd  = *(const float4*)(P.deltas[l] + ((size_t)b * N + idx) * 4);
    // Box2BoxTransformLinear decode (same op order as reference, no fma)
    float w = anc.z - anc.x, hgt = anc.w - anc.y;
    float cx = (anc.x + anc.z) * 0.5f, cy = (anc.y + anc.w) * 0.5f;
    float x1 = cx - dd.x * w;
    float y1 = cy - dd.y * hgt;
    float x2 = cx + dd.z * w;
    float y2 = cy + dd.w * hgt;
    x1 = fminf(fmaxf(x1, 0.0f), 1024.0f);
    y1 = fminf(fmaxf(y1, 0.0f), 1024.0f);
    x2 = fminf(fmaxf(x2, 0.0f), 1024.0f);
    y2 = fminf(fmaxf(y2, 0.0f), 1024.0f);
    bool valid = ((x2 - x1) > 0.0f) && ((y2 - y1) > 0.0f);
    P.scores[sbase + r] = valid ? s : -INFINITY;
    *(float4*)(P.boxes + (sbase + r) * 4) = make_float4(x1, y1, x2, y2);
  }
}

// ---------------- Phase 2a: suppression bitmask (per level) ---------------
// One lane per row i; all lanes sweep the same j together -> every LDS read
// of box j is a same-address broadcast (zero bank conflicts). Boxes stored
// SoA, zero-padded to 1024 so no j<K guard is needed (pad IoU == 0).
__global__ __launch_bounds__(64) void k_mask(RPNParams P) {
  int bl = blockIdx.x, b = bl / 5, l = bl % 5;
  int K = c_K[l];
  int yg = blockIdx.y;   // rows yg*64 .. yg*64+63
  int zc = blockIdx.z;   // column half
  float off = (float)l * 1025.0f;  // lvl * (IMG + 1) — replicate offset rounding!
  size_t sbase = ((size_t)b * 5 + l) * 1024;
  __shared__ float bx1[1024], by1[1024], bx2[1024], by2[1024], barea[1024];
  int tid = threadIdx.x;
  for (int i = tid; i < 1024; i += 64) {
    float4 v = make_float4(0.f, 0.f, 0.f, 0.f);
    if (i < K) {
      v = ((const float4*)P.boxes)[sbase + i];
      v.x += off; v.y += off; v.z += off; v.w += off;
    }
    bx1[i] = v.x; by1[i] = v.y; bx2[i] = v.z; by2[i] = v.w;
    barea[i] = fmaxf(v.z - v.x, 0.0f) * fmaxf(v.w - v.y, 0.0f);
  }
  __syncthreads();
  int i = yg * 64 + tid;
  if (i >= K) return;  // (after the barrier; no further barriers below)
  float x1 = bx1[i], y1 = by1[i], x2 = bx2[i], y2 = by2[i], ai = barea[i];
  unsigned int* mrow = P.mask + (sbase + (size_t)i) * 32;
  int w0 = (yg * 64 + 1) >> 5;      // wave-uniform first word with any j > row
  int nw = 32 - w0;
  int half0 = (nw + 1) >> 1;
  int wbeg = (zc == 0) ? w0 : (w0 + half0);
  int wend = (zc == 0) ? (w0 + half0) : 32;
  if (zc == 0)
    for (int w = 0; w < w0; ++w) mrow[w] = 0u;  // low words: all j <= min row
  for (int w = wbeg; w < wend; ++w) {
    unsigned int bits = 0u;
    int j0 = w << 5;
    for (int jj = 0; jj < 32; ++jj) {
      int j = j0 + jj;
      float xx1 = fmaxf(x1, bx1[j]);
      float yy1 = fmaxf(y1, by1[j]);
      float xx2 = fminf(x2, bx2[j]);
      float yy2 = fminf(y2, by2[j]);
      float ww = fmaxf(xx2 - xx1, 0.0f);
      float hh = fmaxf(yy2 - yy1, 0.0f);
      float inter = ww * hh;
      float uni = ai + barea[j] - inter + 1e-8f;  // ((ai+aj)-inter)+eps
      if ((inter / uni > 0.7f) && (j > i)) bits |= (1u << jj);
    }
    mrow[w] = bits;
  }
}

// ---------------- Phase 2b: serial greedy sweep (1 wave / (img,lvl)) ------
__global__ __launch_bounds__(1024) void k_sweep(RPNParams P) {
  int bl = blockIdx.x, b = bl / 5, l = bl % 5;
  int K = c_K[l];
  size_t sbase = ((size_t)b * 5 + l) * 1024;
  __shared__ unsigned long long lmask[16 * 1000];  // 125 KiB
  int tid = threadIdx.x;
  const unsigned long long* gm = (const unsigned long long*)(P.mask + sbase * 32);
  for (int i = tid; i < K * 16; i += 1024) lmask[i] = gm[i];
  __syncthreads();
  if (tid < 64) {
    int lane = tid;
    unsigned long long kw = 0ull;  // lanes 0..15 hold keep words
    for (int g = 0; g < 16; ++g) {
      int e = g * 64 + lane;
      bool pred = (e < K) && (P.scores[sbase + e] > -INFINITY);
      unsigned long long m = __ballot(pred);
      if (lane == g) kw = m;
    }
    for (int i = 0; i < K; ++i) {
      unsigned long long w64 = shfl64(kw, i >> 6);
      if ((w64 >> (i & 63)) & 1ull) {
        kw &= ~lmask[i * 16 + (lane & 15)];
      }
    }
    for (int g = 0; g < 16; ++g) {
      unsigned long long w64 = shfl64(kw, g);
      int e = g * 64 + lane;
      if (e < K) P.keep[sbase + e] = (unsigned char)((w64 >> lane) & 1ull);
    }
  }
}

// ------- Phase 3: per-image 5-way merge-by-rank + keep-partition + out ----
// Each per-level list from k_select is score-desc sorted except scattered
// -inf (invalid) entries. Step 1: stable-partition each level list so -inf
// entries go to the tail (tail ties are ordered by concat idx asc == correct
// sorted order) -> each list becomes STRICTLY descending in composite key.
// Step 2: global rank of each element = own position + sum over other lists
// of (count of keys greater), via 4 binary searches. Step 3: scatter; then
// stable keep-partition in rank order and write the output (same semantics
// as the previous bitonic version, ~8x less LDS traffic, 91 -> ~20 barriers).
__global__ __launch_bounds__(1024) void k_merge(RPNParams P) {
  int b = blockIdx.x;
  __shared__ unsigned long long keyL[5][1000];  // 40 KB, strictly desc per level
  __shared__ unsigned short srt[4768];          // rank -> concat idx
  __shared__ unsigned int wsum[16];
  __shared__ unsigned int sTot;
  int tid = threadIdx.x;
  int lane = tid & 63, wid = tid >> 6;

  // ---- Step 1: load + stable partition (valid first) per level ----
  for (int l = 0; l < 5; ++l) {
    int Kl = c_K[l];
    int r = tid;
    bool active = r < Kl;
    unsigned long long k = 0ull;
    bool flag = false;
    if (active) {
      float s = P.scores[((size_t)b * 5 + l) * 1024 + r];
      unsigned int fk = fkey(s);
      flag = fk > 0x007FFFFFu;  // score > -inf
      unsigned int cidx = (unsigned int)(l * 1000 + r);
      k = ((unsigned long long)fk << 32) |
          (unsigned long long)(0xFFFFFFFFu - cidx);
    }
    unsigned int fv = flag ? 1u : 0u;
    unsigned int v = fv;
    for (int d = 1; d < 64; d <<= 1) {
      unsigned int n = __shfl_up(v, (unsigned int)d, 64);
      if (lane >= d) v += n;
    }
    if (lane == 63) wsum[wid] = v;
    __syncthreads();
    if (tid == 0) {
      unsigned int acc = 0;
      for (int w = 0; w < 16; ++w) { unsigned int x = wsum[w]; wsum[w] = acc; acc += x; }
      sTot = acc;
    }
    __syncthreads();
    unsigned int excl = wsum[wid] + (v - fv);
    unsigned int nValid = sTot;
    if (active) {
      unsigned int dest = flag ? excl : (nValid + ((unsigned int)r - excl));
      keyL[l][dest] = k;
    }
    __syncthreads();
  }

  // ---- Step 2: global rank via binary search in the other 4 lists ----
  for (int e = tid; e < 4768; e += 1024) {
    int l = (e < 4000) ? (e / 1000) : 4;
    int p = e - l * 1000;
    unsigned long long k = keyL[l][p];
    int rank = p;
    #pragma unroll
    for (int l2 = 0; l2 < 5; ++l2) {
      if (l2 == l) continue;
      int lo = 0, hi = c_K[l2];
      while (lo < hi) {
        int mid = (lo + hi) >> 1;
        if (keyL[l2][mid] > k) lo = mid + 1; else hi = mid;
      }
      rank += lo;
    }
    srt[rank] = (unsigned short)(0xFFFFFFFFu - (unsigned int)(k & 0xFFFFFFFFu));
  }
  __syncthreads();

  // ---- Step 3: keep flags for 5 contiguous sorted slots per thread ----
  int base = tid * 5;
  unsigned char lf[5];
  unsigned short lc[5];
  unsigned int lsum = 0;
  for (int q = 0; q < 5; ++q) {
    int i = base + q;
    unsigned char f = 0; unsigned short cx = 0;
    if (i < 4768) {
      cx = srt[i];
      int l = cx / 1000;
      int r = (int)cx - l * 1000;
      f = P.keep[((size_t)b * 5 + l) * 1024 + r];
    }
    lf[q] = f; lc[q] = cx; lsum += f;
  }
  unsigned int v = lsum;
  for (int d = 1; d < 64; d <<= 1) {
    unsigned int n = __shfl_up(v, (unsigned int)d, 64);
    if (lane >= d) v += n;
  }
  if (lane == 63) wsum[wid] = v;
  __syncthreads();
  if (tid == 0) {
    unsigned int acc = 0;
    for (int w = 0; w < 16; ++w) { unsigned int x = wsum[w]; wsum[w] = acc; acc += x; }
    sTot = acc;
  }
  __syncthreads();
  unsigned int excl = wsum[wid] + (v - lsum);  // kept count before slot `base`
  unsigned int tot = sTot;
  for (int q = 0; q < 5; ++q) {
    int i = base + q;
    if (i >= 4768) break;
    unsigned int cidx = (unsigned int)lc[q];
    int l = (int)(cidx / 1000u);
    int r = (int)cidx - l * 1000;
    size_t sb = ((size_t)b * 5 + l) * 1024 + r;
    unsigned char f = lf[q];
    unsigned int pos = f ? excl : (tot + ((unsigned int)i - excl));
    excl += f;
    if (pos < 1000u) {
      float4 bx = ((const float4*)P.boxes)[sb];
      float sc = f ? P.scores[sb] : -INFINITY;
      float* o = P.out + ((size_t)b * 1000 + pos) * 5;
      o[0] = bx.x; o[1] = bx.y; o[2] = bx.z; o[3] = bx.w; o[4] = sc;
    }
  }
}

}  // namespace

extern "C" void kernel_launch(void* const* d_in, const int* in_sizes, int n_in,
                              void* d_out, int out_size, void* d_ws, size_t ws_size,
                              hipStream_t stream) {
  (void)out_size; (void)ws_size;
  RPNParams P;
  // setup_inputs() dict order is interleaved (deltas,ctr,anchors per level);
  // detect by anchors_p2 size in slot 2 in case the harness grouped by arg.
  bool interleaved = (n_in >= 3) && (in_sizes[2] == 786432);
  for (int l = 0; l < 5; ++l) {
    if (interleaved) {
      P.deltas[l]  = (const float*)d_in[3 * l + 0];
      P.ctr[l]     = (const float*)d_in[3 * l + 1];
      P.anchors[l] = (const float*)d_in[3 * l + 2];
    } else {
      P.deltas[l]  = (const float*)d_in[l];
      P.ctr[l]     = (const float*)d_in[5 + l];
      P.anchors[l] = (const float*)d_in[10 + l];
    }
  }
  char* ws = (char*)d_ws;
  P.scores = (float*)(ws + 0);               // 163840 B
  P.boxes  = (float*)(ws + 163840);          // 655360 B
  P.keep   = (unsigned char*)(ws + 819200);  // 40960 B
  P.mask   = (unsigned int*)(ws + 860160);   // 5242880 B
  P.ghist0 = (unsigned int*)(ws + 6103040);  // 40960 B
  P.ghist1 = (unsigned int*)(ws + 6144000);  // 40960 B
  P.out    = (float*)d_out;

  hipMemsetAsync(ws + 6103040, 0, 81920, stream);  // zero both histograms
  hipLaunchKernelGGL(k_hist0, dim3(40, 32), dim3(256), 0, stream, P);
  hipLaunchKernelGGL(k_hist1, dim3(40, 32), dim3(256), 0, stream, P);
  hipLaunchKernelGGL(k_select, dim3(40), dim3(1024), 0, stream, P);
  hipLaunchKernelGGL(k_mask, dim3(40, 16, 2), dim3(64), 0, stream, P);
  hipLaunchKernelGGL(k_sweep, dim3(40), dim3(1024), 0, stream, P);
  hipLaunchKernelGGL(k_merge, dim3(8), dim3(1024), 0, stream, P);
}